// Round 2
// baseline (374.388 us; speedup 1.0000x reference)
//
#include <hip/hip_runtime.h>
#include <hip/hip_bf16.h>

#define N_B 2
#define SEQ 2048
#define NH 16
#define DH 64
#define EMB 1024

typedef __bf16 bf16;
typedef __attribute__((ext_vector_type(8))) __bf16 bf16x8;
typedef __attribute__((ext_vector_type(4))) __bf16 bf16x4;
typedef __attribute__((ext_vector_type(4))) float f32x4;

// workspace layout (bytes)
#define OFF_MQK  0                         // 64*64 bf16      = 8 KB
#define OFF_WO2  8192                      // 1024*1024 bf16  = 2 MB
#define OFF_K2   (8192 + 2097152)          // [N][H][L][64] bf16 = 8 MB
#define OFF_VT   (OFF_K2 + 8388608)        // [N][H][64][L] bf16 = 8 MB
#define OFF_A2   (OFF_VT + 8388608)        // [N][L][1024] bf16  = 8 MB
#define OFF_MB   (OFF_A2 + 8388608)        // [N][L][32] u64     = 1 MB

__device__ __forceinline__ f32x4 mfma16(bf16x8 a, bf16x8 b, f32x4 c) {
  return __builtin_amdgcn_mfma_f32_16x16x32_bf16(a, b, c, 0, 0, 0);
}

// ---------------- P0: Mqk = (Wq^T Wk) / 8, to bf16 -------------------------
__global__ __launch_bounds__(256) void prep0(const float* __restrict__ Wq,
                                             const float* __restrict__ Wk,
                                             bf16* __restrict__ mqk) {
  __shared__ float wq[64 * 64];
  __shared__ float wk[64 * 64];
  int tid = threadIdx.x;
  for (int i = tid; i < 4096; i += 256) { wq[i] = Wq[i]; wk[i] = Wk[i]; }
  __syncthreads();
  for (int idx = tid; idx < 4096; idx += 256) {
    int d1 = idx >> 6, d2 = idx & 63;
    float s = 0.f;
#pragma unroll
    for (int e = 0; e < 64; ++e) s += wq[e * 64 + d1] * wk[e * 64 + d2];
    mqk[idx] = (bf16)(s * 0.125f);
  }
}

// ---------------- P1: Wo2[e][h*64+d'] = sum_d Wo[e][h*64+d] * Wv[d][d'] ----
__global__ __launch_bounds__(256) void prep1(const float* __restrict__ Wo,
                                             const float* __restrict__ Wv,
                                             bf16* __restrict__ wo2) {
  int e = blockIdx.x;
  __shared__ float wv[64 * 64];
  __shared__ float worow[1024];
  int tid = threadIdx.x;
  for (int i = tid; i < 4096; i += 256) wv[i] = Wv[i];
  for (int i = tid; i < 1024; i += 256) worow[i] = Wo[(size_t)e * 1024 + i];
  __syncthreads();
  int c0 = tid * 4;
#pragma unroll
  for (int j = 0; j < 4; ++j) {
    int c = c0 + j;
    int hb = c & ~63, dp = c & 63;
    float s = 0.f;
#pragma unroll
    for (int d = 0; d < 64; ++d) s += worow[hb + d] * wv[d * 64 + dp];
    wo2[(size_t)e * 1024 + c] = (bf16)s;
  }
}

// ---------------- P2a: k2[n][h][l][d1] = sum_d2 k[n][l][h*64+d2]*Mqk[d1][d2]
__global__ __launch_bounds__(256) void proj_k2(const float* __restrict__ keys,
                                               const bf16* __restrict__ mqk,
                                               bf16* __restrict__ k2b) {
  int blk = blockIdx.x;  // n*NH*32 + h*32 + lt
  int lt = blk & 31, h = (blk >> 5) & 15, n = blk >> 9;
  int tid = threadIdx.x, wave = tid >> 6, lane = tid & 63;
  int g = lane >> 4, c = lane & 15;
  bf16x8 am[4][2];
#pragma unroll
  for (int t = 0; t < 4; ++t)
#pragma unroll
    for (int s = 0; s < 2; ++s)
      am[t][s] = *(const bf16x8*)(mqk + (16 * t + c) * 64 + 32 * s + 8 * g);
  int l = lt * 64 + wave * 16 + c;
  const float* krow = keys + ((size_t)(n * SEQ + l)) * EMB + h * DH;
  bf16x8 bfr[2];
#pragma unroll
  for (int s = 0; s < 2; ++s) {
    f32x4 x0 = *(const f32x4*)(krow + 32 * s + 8 * g);
    f32x4 x1 = *(const f32x4*)(krow + 32 * s + 8 * g + 4);
    bf16x8 t;
#pragma unroll
    for (int i = 0; i < 4; ++i) { t[i] = (bf16)x0[i]; t[4 + i] = (bf16)x1[i]; }
    bfr[s] = t;
  }
  bf16* obase = k2b + (((size_t)(n * NH + h)) * SEQ + l) * DH;
#pragma unroll
  for (int t = 0; t < 4; ++t) {
    f32x4 a = {0.f, 0.f, 0.f, 0.f};
    a = mfma16(am[t][0], bfr[0], a);
    a = mfma16(am[t][1], bfr[1], a);
    bf16x4 w;
#pragma unroll
    for (int r = 0; r < 4; ++r) w[r] = (bf16)a[r];
    *(bf16x4*)(obase + 16 * t + 4 * g) = w;
  }
}

// ---------------- P2b: vbT[n][h][d][l] = bf16(values[n][l][h*64+d]) --------
__global__ __launch_bounds__(256) void vtrans(const float* __restrict__ values,
                                              bf16* __restrict__ vbT) {
  int blk = blockIdx.x;  // n*NH*32 + h*32 + lt
  int lt = blk & 31, h = (blk >> 5) & 15, n = blk >> 9;
  int tid = threadIdx.x;
  __shared__ float lds[64][65];
  {
    int r = tid >> 2, cg = (tid & 3) * 16;
    const float* vrow = values + ((size_t)(n * SEQ + lt * 64 + r)) * EMB + h * DH + cg;
#pragma unroll
    for (int j = 0; j < 16; j += 4) {
      f32x4 x = *(const f32x4*)(vrow + j);
      lds[r][cg + j + 0] = x[0];
      lds[r][cg + j + 1] = x[1];
      lds[r][cg + j + 2] = x[2];
      lds[r][cg + j + 3] = x[3];
    }
  }
  __syncthreads();
  {
    int d = tid >> 2, lb = (tid & 3) * 16;
    bf16x8 w0, w1;
#pragma unroll
    for (int j = 0; j < 8; ++j) w0[j] = (bf16)lds[lb + j][d];
#pragma unroll
    for (int j = 0; j < 8; ++j) w1[j] = (bf16)lds[lb + 8 + j][d];
    bf16* orow = vbT + (((size_t)(n * NH + h)) * DH + d) * SEQ + lt * 64 + lb;
    *(bf16x8*)(orow) = w0;
    *(bf16x8*)(orow + 8) = w1;
  }
}

// ---------------- P2c: pack mask bits: mb[n][q][kw] ------------------------
__global__ __launch_bounds__(256) void maskpack(const int* __restrict__ mask,
                                                unsigned long long* __restrict__ mb) {
  int w = blockIdx.x * 4 + (threadIdx.x >> 6);
  int lane = threadIdx.x & 63;
  int v = mask[(size_t)w * 64 + lane];
  unsigned long long b = __ballot(v != 0);
  if (lane == 0) mb[w] = b;
}

// ---------------- F: flash attention ---------------------------------------
__global__ __launch_bounds__(256) void attn(const float* __restrict__ qraw,
                                            const bf16* __restrict__ k2b,
                                            const bf16* __restrict__ vbT,
                                            const unsigned long long* __restrict__ mb,
                                            bf16* __restrict__ a2) {
  int blk = blockIdx.x;  // n*NH*32 + h*32 + qt
  int qt = blk & 31, h = (blk >> 5) & 15, n = blk >> 9;
  int tid = threadIdx.x, wave = tid >> 6, lane = tid & 63;
  int g = lane >> 4, c = lane & 15;
  int q = qt * 64 + wave * 16 + c;

  __shared__ bf16 plds[4][16][72];  // per-wave P[q][kk], stride 72 -> 2-way banks

  // Q as B-operand fragments: lane holds q=c, d = 32s + 8g + i
  bf16x8 qf[2];
  {
    const float* qrow = qraw + ((size_t)(n * SEQ + q)) * EMB + h * DH;
#pragma unroll
    for (int s = 0; s < 2; ++s) {
      f32x4 x0 = *(const f32x4*)(qrow + 32 * s + 8 * g);
      f32x4 x1 = *(const f32x4*)(qrow + 32 * s + 8 * g + 4);
      bf16x8 t;
#pragma unroll
      for (int i = 0; i < 4; ++i) { t[i] = (bf16)x0[i]; t[4 + i] = (bf16)x1[i]; }
      qf[s] = t;
    }
  }
  const bf16* kb = k2b + ((size_t)(n * NH + h)) * SEQ * DH;
  const bf16* vt = vbT + ((size_t)(n * NH + h)) * DH * SEQ;
  const unsigned long long* mrow = mb + ((size_t)(n * SEQ + q)) * (SEQ / 64);

  f32x4 oacc[4];
#pragma unroll
  for (int dt = 0; dt < 4; ++dt) oacc[dt] = (f32x4){0.f, 0.f, 0.f, 0.f};
  float mrun = -1e30f, lrun = 0.f;

  for (int kt = 0; kt < SEQ / 64; ++kt) {
    const bf16* ktb = kb + kt * 64 * DH;
    f32x4 sacc[4];
#pragma unroll
    for (int t = 0; t < 4; ++t) {
      f32x4 a = {0.f, 0.f, 0.f, 0.f};
      a = mfma16(*(const bf16x8*)(ktb + (16 * t + c) * DH + 8 * g), qf[0], a);
      a = mfma16(*(const bf16x8*)(ktb + (16 * t + c) * DH + 32 + 8 * g), qf[1], a);
      sacc[t] = a;
    }
    unsigned long long mw = mrow[kt];
    float sv[16];
    float tmax = -1e30f;
#pragma unroll
    for (int t = 0; t < 4; ++t)
#pragma unroll
      for (int r = 0; r < 4; ++r) {
        int kk = 16 * t + 4 * g + r;
        float x = sacc[t][r];
        x = ((mw >> kk) & 1ull) ? x : -1e20f;
        sv[4 * t + r] = x;
        tmax = fmaxf(tmax, x);
      }
    tmax = fmaxf(tmax, __shfl_xor(tmax, 16));
    tmax = fmaxf(tmax, __shfl_xor(tmax, 32));
    float mnew = fmaxf(mrun, tmax);
    float scale = __expf(mrun - mnew);
    float psum = 0.f;
#pragma unroll
    for (int t = 0; t < 4; ++t) {
      bf16x4 w;
#pragma unroll
      for (int r = 0; r < 4; ++r) {
        float p = __expf(sv[4 * t + r] - mnew);
        psum += p;
        w[r] = (bf16)p;
      }
      *(bf16x4*)&plds[wave][c][16 * t + 4 * g] = w;
    }
    psum += __shfl_xor(psum, 16);
    psum += __shfl_xor(psum, 32);
    lrun = lrun * scale + psum;
    mrun = mnew;
#pragma unroll
    for (int dt = 0; dt < 4; ++dt) {
      oacc[dt][0] *= scale; oacc[dt][1] *= scale;
      oacc[dt][2] *= scale; oacc[dt][3] *= scale;
    }
    const bf16* vtb = vt + kt * 64;
#pragma unroll
    for (int s = 0; s < 2; ++s) {
      bf16x8 pf = *(const bf16x8*)&plds[wave][c][32 * s + 8 * g];
#pragma unroll
      for (int dt = 0; dt < 4; ++dt) {
        bf16x8 vf = *(const bf16x8*)(vtb + (size_t)(16 * dt + c) * SEQ + 32 * s + 8 * g);
        oacc[dt] = mfma16(vf, pf, oacc[dt]);
      }
    }
  }
  float inv = 1.0f / lrun;
  bf16* orow = a2 + ((size_t)(n * SEQ + q)) * EMB + h * DH;
#pragma unroll
  for (int dt = 0; dt < 4; ++dt) {
    bf16x4 w;
#pragma unroll
    for (int r = 0; r < 4; ++r) w[r] = (bf16)(oacc[dt][r] * inv);
    *(bf16x4*)(orow + 16 * dt + 4 * g) = w;
  }
}

// ---------------- G: out[m][e] = sum_c a2[m][c]*Wo2[e][c] + bo[e] ----------
__global__ __launch_bounds__(256) void out_gemm(const bf16* __restrict__ a2,
                                                const bf16* __restrict__ wo2,
                                                const float* __restrict__ bo,
                                                float* __restrict__ out) {
  int blk = blockIdx.x;  // mt*16 + et
  int et = blk & 15, mt = blk >> 4;
  int tid = threadIdx.x, wave = tid >> 6, lane = tid & 63;
  int g = lane >> 4, c = lane & 15;
  int m = mt * 64 + wave * 16 + c;
  int e0 = et * 64;
  const bf16* arow = a2 + (size_t)m * EMB;
  f32x4 acc[4];
#pragma unroll
  for (int t = 0; t < 4; ++t) acc[t] = (f32x4){0.f, 0.f, 0.f, 0.f};
  for (int k = 0; k < EMB; k += 32) {
    bf16x8 bf = *(const bf16x8*)(arow + k + 8 * g);
#pragma unroll
    for (int t = 0; t < 4; ++t) {
      bf16x8 af = *(const bf16x8*)(wo2 + (size_t)(e0 + 16 * t + c) * EMB + k + 8 * g);
      acc[t] = mfma16(af, bf, acc[t]);
    }
  }
#pragma unroll
  for (int t = 0; t < 4; ++t) {
    int e = e0 + 16 * t + 4 * g;
    f32x4 b = *(const f32x4*)(bo + e);
    f32x4 w;
#pragma unroll
    for (int r = 0; r < 4; ++r) w[r] = acc[t][r] + b[r];
    *(f32x4*)(out + (size_t)m * EMB + e) = w;
  }
}

extern "C" void kernel_launch(void* const* d_in, const int* in_sizes, int n_in,
                              void* d_out, int out_size, void* d_ws, size_t ws_size,
                              hipStream_t stream) {
  const float* values = (const float*)d_in[0];
  const float* keys   = (const float*)d_in[1];
  const float* query  = (const float*)d_in[2];
  const int*   mask   = (const int*)d_in[3];
  const float* Wv     = (const float*)d_in[4];
  const float* Wk     = (const float*)d_in[5];
  const float* Wq     = (const float*)d_in[6];
  const float* Wo     = (const float*)d_in[7];
  const float* bo     = (const float*)d_in[8];

  char* ws = (char*)d_ws;
  bf16* mqk = (bf16*)(ws + OFF_MQK);
  bf16* wo2 = (bf16*)(ws + OFF_WO2);
  bf16* k2  = (bf16*)(ws + OFF_K2);
  bf16* vt  = (bf16*)(ws + OFF_VT);
  bf16* a2  = (bf16*)(ws + OFF_A2);
  unsigned long long* mb = (unsigned long long*)(ws + OFF_MB);

  prep0<<<1, 256, 0, stream>>>(Wq, Wk, mqk);
  prep1<<<1024, 256, 0, stream>>>(Wo, Wv, wo2);
  proj_k2<<<1024, 256, 0, stream>>>(keys, mqk, k2);
  vtrans<<<1024, 256, 0, stream>>>(values, vt);
  maskpack<<<32768, 256, 0, stream>>>(mask, mb);
  attn<<<1024, 256, 0, stream>>>(query, k2, vt, mb, a2);
  out_gemm<<<1024, 256, 0, stream>>>(a2, wo2, bo, (float*)d_out);
}

// Round 4
// 169.022 us; speedup vs baseline: 2.2150x; 2.2150x over previous
//
#include <hip/hip_runtime.h>
#include <hip/hip_bf16.h>

#define SEQ 2048
#define NH 16
#define DH 64
#define EMB 1024

typedef __bf16 bf16;
typedef __attribute__((ext_vector_type(8))) __bf16 bf16x8;
typedef __attribute__((ext_vector_type(4))) __bf16 bf16x4;
typedef __attribute__((ext_vector_type(4))) float f32x4;
typedef __attribute__((ext_vector_type(4))) unsigned int u32x4;
typedef unsigned long long u64;

// workspace layout (bytes)
#define OFF_MQK  0                         // 64*64 bf16      = 8 KB
#define OFF_WO2  8192                      // 1024*1024 bf16  = 2 MB (fragment order)
#define OFF_K2   (8192 + 2097152)          // [N][H][32 kt][8KB frag tiles] = 8 MB
#define OFF_VT   (OFF_K2 + 8388608)        // [N][H][32 kt][8KB frag tiles] = 8 MB
#define OFF_A2   (OFF_VT + 8388608)        // [N][L][1024] bf16  = 8 MB
#define OFF_MB   (OFF_A2 + 8388608)        // [N][L][32] u64     = 1 MB

__device__ __forceinline__ f32x4 mfma16(bf16x8 a, bf16x8 b, f32x4 c) {
  return __builtin_amdgcn_mfma_f32_16x16x32_bf16(a, b, c, 0, 0, 0);
}

#define GL16(g, l)                                                            \
  __builtin_amdgcn_global_load_lds(                                           \
      (const __attribute__((address_space(1))) void*)(g),                     \
      (__attribute__((address_space(3))) void*)(l), 16, 0, 0)

// ---------------- P0: Mqk = (Wq^T Wk) / 8, to bf16 -------------------------
__global__ __launch_bounds__(256) void prep0(const float* __restrict__ Wq,
                                             const float* __restrict__ Wk,
                                             bf16* __restrict__ mqk) {
  __shared__ float wq[64 * 64];
  __shared__ float wk[64 * 64];
  int tid = threadIdx.x;
  for (int i = tid; i < 4096; i += 256) { wq[i] = Wq[i]; wk[i] = Wk[i]; }
  __syncthreads();
  for (int idx = tid; idx < 4096; idx += 256) {
    int d1 = idx >> 6, d2 = idx & 63;
    float s = 0.f;
#pragma unroll
    for (int e = 0; e < 64; ++e) s += wq[e * 64 + d1] * wk[e * 64 + d2];
    mqk[idx] = (bf16)(s * 0.125f);
  }
}

// ---------------- P1: Wo2 = Wo·(blockdiag Wv), fragment-ordered ------------
// wo2f tile (et,kc): 4KB = [t(4)][lane(g,c)][16B]; lane holds
// Wo2[et*64+16t+c][kc*32+8g .. +7]
__global__ __launch_bounds__(256) void prep1(const float* __restrict__ Wo,
                                             const float* __restrict__ Wv,
                                             bf16* __restrict__ wo2f) {
  int e = blockIdx.x;
  __shared__ float wv[64 * 64];
  __shared__ float worow[1024];
  int tid = threadIdx.x;
  for (int i = tid; i < 4096; i += 256) wv[i] = Wv[i];
  for (int i = tid; i < 1024; i += 256) worow[i] = Wo[(size_t)e * 1024 + i];
  __syncthreads();
  int c0 = tid * 4;
  bf16x4 w;
#pragma unroll
  for (int j = 0; j < 4; ++j) {
    int col = c0 + j;
    int hb = col & ~63, dp = col & 63;
    float s = 0.f;
#pragma unroll
    for (int d = 0; d < 64; ++d) s += worow[hb + d] * wv[d * 64 + dp];
    w[j] = (bf16)s;
  }
  int et = e >> 6, t = (e >> 4) & 3, cc = e & 15;
  int kc = c0 >> 5, gg = (c0 >> 3) & 3, half = (c0 >> 2) & 1;
  char* dst = (char*)wo2f + ((size_t)(et * 32 + kc)) * 4096 + t * 1024 +
              (gg * 16 + cc) * 16 + 8 * half;
  *(bf16x4*)dst = w;
}

// ---------------- P2a: projected K, fragment-ordered -----------------------
// k2f tile (n,h,kt): 8KB = [chunk(2t+s)][lane(g,c)][16B]; lane holds
// K2'[kt*64+16t+c][32s+8g .. +7]
__global__ __launch_bounds__(256) void proj_k2(const float* __restrict__ keys,
                                               const bf16* __restrict__ mqk,
                                               bf16* __restrict__ k2f) {
  int blk = blockIdx.x;  // n*NH*32 + h*32 + lt
  int lt = blk & 31, h = (blk >> 5) & 15, n = blk >> 9;
  int tid = threadIdx.x, wave = tid >> 6, lane = tid & 63;
  int g = lane >> 4, c = lane & 15;
  bf16x8 am[4][2];
#pragma unroll
  for (int t = 0; t < 4; ++t)
#pragma unroll
    for (int s = 0; s < 2; ++s)
      am[t][s] = *(const bf16x8*)(mqk + (16 * t + c) * 64 + 32 * s + 8 * g);
  int l = lt * 64 + wave * 16 + c;
  const float* krow = keys + ((size_t)(n * SEQ + l)) * EMB + h * DH;
  bf16x8 bfr[2];
#pragma unroll
  for (int s = 0; s < 2; ++s) {
    f32x4 x0 = *(const f32x4*)(krow + 32 * s + 8 * g);
    f32x4 x1 = *(const f32x4*)(krow + 32 * s + 8 * g + 4);
    bf16x8 t;
#pragma unroll
    for (int i = 0; i < 4; ++i) { t[i] = (bf16)x0[i]; t[4 + i] = (bf16)x1[i]; }
    bfr[s] = t;
  }
  char* tb = (char*)k2f + (size_t)((n * NH + h) * 32 + lt) * 8192 + wave * 2048;
#pragma unroll
  for (int t = 0; t < 4; ++t) {
    f32x4 a = {0.f, 0.f, 0.f, 0.f};
    a = mfma16(am[t][0], bfr[0], a);
    a = mfma16(am[t][1], bfr[1], a);
    bf16x4 w;
#pragma unroll
    for (int r = 0; r < 4; ++r) w[r] = (bf16)a[r];
    char* dst = tb + (t >> 1) * 1024 + ((2 * (t & 1) + (g >> 1)) * 16 + c) * 16 +
                8 * (g & 1);
    *(bf16x4*)dst = w;
  }
}

// ---------------- P2b: V^T, fragment-ordered -------------------------------
// vtf tile (n,h,kt): 8KB = [chunk(2dt+s)][lane(g,c)][16B]; lane holds
// V^T[16dt+c][kt*64+32s+8g .. +7]
__global__ __launch_bounds__(256) void vtrans(const float* __restrict__ values,
                                              bf16* __restrict__ vtf) {
  int blk = blockIdx.x;  // n*NH*32 + h*32 + lt
  int lt = blk & 31, h = (blk >> 5) & 15, n = blk >> 9;
  int tid = threadIdx.x;
  __shared__ float lds[64][65];
  {
    int r = tid >> 2, cg = (tid & 3) * 16;
    const float* vrow = values + ((size_t)(n * SEQ + lt * 64 + r)) * EMB + h * DH + cg;
#pragma unroll
    for (int j = 0; j < 16; j += 4) {
      f32x4 x = *(const f32x4*)(vrow + j);
      lds[r][cg + j + 0] = x[0];
      lds[r][cg + j + 1] = x[1];
      lds[r][cg + j + 2] = x[2];
      lds[r][cg + j + 3] = x[3];
    }
  }
  __syncthreads();
  {
    int d = tid >> 2, q16 = tid & 3, lb = q16 * 16;
    bf16x8 w0, w1;
#pragma unroll
    for (int j = 0; j < 8; ++j) w0[j] = (bf16)lds[lb + j][d];
#pragma unroll
    for (int j = 0; j < 8; ++j) w1[j] = (bf16)lds[lb + 8 + j][d];
    int dt = d >> 4, cc = d & 15;
    int s = q16 >> 1, gg = 2 * (q16 & 1);
    char* base = (char*)vtf + (size_t)((n * NH + h) * 32 + lt) * 8192 +
                 (2 * dt + s) * 1024;
    *(bf16x8*)(base + (gg * 16 + cc) * 16) = w0;
    *(bf16x8*)(base + ((gg + 1) * 16 + cc) * 16) = w1;
  }
}

// ---------------- P2c: pack mask bits: mb[n][q][kw] ------------------------
__global__ __launch_bounds__(256) void maskpack(const int* __restrict__ mask,
                                                u64* __restrict__ mb) {
  int w = blockIdx.x * 4 + (threadIdx.x >> 6);
  int lane = threadIdx.x & 63;
  int v = mask[(size_t)w * 64 + lane];
  u64 b = __ballot(v != 0);
  if (lane == 0) mb[w] = b;
}

// ---------------- F: flash attention (LDS-staged, dbuf, in-reg P) ----------
__global__ __launch_bounds__(256) void attn(const float* __restrict__ qraw,
                                            const bf16* __restrict__ k2f,
                                            const bf16* __restrict__ vtf,
                                            const u64* __restrict__ mb,
                                            bf16* __restrict__ a2) {
  int blk = blockIdx.x;  // n*NH*32 + h*32 + qt
  int qt = blk & 31, h = (blk >> 5) & 15, n = blk >> 9;
  int tid = threadIdx.x, wave = tid >> 6, lane = tid & 63;
  int g = lane >> 4, c = lane & 15;
  int q = qt * 64 + wave * 16 + c;

  __shared__ bf16 kv[2][8192];  // [buf][K 8KB | V 8KB]

  // Q as B-operand fragments: lane holds q=c, d = 32s + 8g + i
  bf16x8 qf[2];
  {
    const float* qrow = qraw + ((size_t)(n * SEQ + q)) * EMB + h * DH;
#pragma unroll
    for (int s = 0; s < 2; ++s) {
      f32x4 x0 = *(const f32x4*)(qrow + 32 * s + 8 * g);
      f32x4 x1 = *(const f32x4*)(qrow + 32 * s + 8 * g + 4);
      bf16x8 t;
#pragma unroll
      for (int i = 0; i < 4; ++i) { t[i] = (bf16)x0[i]; t[4 + i] = (bf16)x1[i]; }
      qf[s] = t;
    }
  }
  const char* kbase = (const char*)k2f + (size_t)(n * NH + h) * 32 * 8192;
  const char* vbase = (const char*)vtf + (size_t)(n * NH + h) * 32 * 8192;
  const u64* mrow = mb + ((size_t)(n * SEQ + q)) * 32;

  int lofs = lane * 16;          // per-lane global offset within a 4KB stage
  int wofs = wave * 1024;        // wave-uniform LDS offset

  // prologue: stage tile 0 into buf 0 (wave-uniform LDS dest; HW adds lane*16)
  {
    char* lb = (char*)&kv[0][0] + wofs;
    const char* kg = kbase + wofs + lofs;
    const char* vg = vbase + wofs + lofs;
    GL16(kg, lb);
    GL16(kg + 4096, lb + 4096);
    GL16(vg, lb + 8192);
    GL16(vg + 4096, lb + 12288);
  }
  u64 mw_next = mrow[0];
  __syncthreads();  // tile 0 staged (full vmcnt/lgkm drain + barrier)

  f32x4 oacc[4];
#pragma unroll
  for (int dt = 0; dt < 4; ++dt) oacc[dt] = (f32x4){0.f, 0.f, 0.f, 0.f};
  float mrun = -1e30f, lrun = 0.f;

  for (int kt = 0; kt < 32; ++kt) {
    int cur = kt & 1;
    u64 mw = mw_next;
    if (kt < 31) {  // issue next-tile staging; overlaps with compute below
      char* lb = (char*)&kv[cur ^ 1][0] + wofs;
      const char* kg = kbase + (size_t)(kt + 1) * 8192 + wofs + lofs;
      const char* vg = vbase + (size_t)(kt + 1) * 8192 + wofs + lofs;
      GL16(kg, lb);
      GL16(kg + 4096, lb + 4096);
      GL16(vg, lb + 8192);
      GL16(vg + 4096, lb + 12288);
      mw_next = mrow[kt + 1];
    }

    const bf16* kb = &kv[cur][0];
    const bf16* vb = &kv[cur][4096];

    // QK^T: D[k-row][q-col]; lane(g,c): q=c, kk=16t+4g+r
    f32x4 sacc[4];
#pragma unroll
    for (int t = 0; t < 4; ++t) {
      f32x4 a = {0.f, 0.f, 0.f, 0.f};
      a = mfma16(*(const bf16x8*)(kb + (2 * t) * 512 + lane * 8), qf[0], a);
      a = mfma16(*(const bf16x8*)(kb + (2 * t + 1) * 512 + lane * 8), qf[1], a);
      sacc[t] = a;
    }
    float sv[16];
    float tmax = -1e30f;
#pragma unroll
    for (int t = 0; t < 4; ++t)
#pragma unroll
      for (int r = 0; r < 4; ++r) {
        int kk = 16 * t + 4 * g + r;
        float x = sacc[t][r];
        x = ((mw >> kk) & 1ull) ? x : -1e20f;
        sv[4 * t + r] = x;
        tmax = fmaxf(tmax, x);
      }
    tmax = fmaxf(tmax, __shfl_xor(tmax, 16));
    tmax = fmaxf(tmax, __shfl_xor(tmax, 32));
    float mnew = fmaxf(mrun, tmax);
    float scl = __expf(mrun - mnew);
    float psum = 0.f;
    unsigned w[4][2];  // packed bf16 pairs: w[t][j] = p[4t+2j] | p[4t+2j+1]<<16
#pragma unroll
    for (int t = 0; t < 4; ++t)
#pragma unroll
      for (int jj = 0; jj < 2; ++jj) {
        float p0 = __expf(sv[4 * t + 2 * jj] - mnew);
        float p1 = __expf(sv[4 * t + 2 * jj + 1] - mnew);
        psum += p0 + p1;
        unsigned short b0 = __builtin_bit_cast(unsigned short, (bf16)p0);
        unsigned short b1 = __builtin_bit_cast(unsigned short, (bf16)p1);
        w[t][jj] = (unsigned)b0 | ((unsigned)b1 << 16);
      }
    psum += __shfl_xor(psum, 16);
    psum += __shfl_xor(psum, 32);
    lrun = lrun * scl + psum;
    mrun = mnew;
#pragma unroll
    for (int dt = 0; dt < 4; ++dt) {
      oacc[dt][0] *= scl; oacc[dt][1] *= scl;
      oacc[dt][2] *= scl; oacc[dt][3] *= scl;
    }
    // P fragments in-register via shuffles:
    // dest lane(g,c) frag s needs kk=32s+8g+i (q=c); sources: lanes
    // srcA=((g&1)<<5)|c (first 4 kk), srcB=srcA+16 (last 4), word 2s+(g>>1)
    int srcA = ((g & 1) << 5) | c;
    int srcB = srcA + 16;
    bool hi2 = (g >> 1) != 0;
    bf16x8 pf[2];
#pragma unroll
    for (int s = 0; s < 2; ++s) {
      unsigned ta0 = (unsigned)__shfl((int)w[2 * s][0], srcA);
      unsigned ta1 = (unsigned)__shfl((int)w[2 * s][1], srcA);
      unsigned tb0 = (unsigned)__shfl((int)w[2 * s + 1][0], srcA);
      unsigned tb1 = (unsigned)__shfl((int)w[2 * s + 1][1], srcA);
      unsigned ua0 = (unsigned)__shfl((int)w[2 * s][0], srcB);
      unsigned ua1 = (unsigned)__shfl((int)w[2 * s][1], srcB);
      unsigned ub0 = (unsigned)__shfl((int)w[2 * s + 1][0], srcB);
      unsigned ub1 = (unsigned)__shfl((int)w[2 * s + 1][1], srcB);
      u32x4 f;
      f[0] = hi2 ? tb0 : ta0;
      f[1] = hi2 ? tb1 : ta1;
      f[2] = hi2 ? ub0 : ua0;
      f[3] = hi2 ? ub1 : ua1;
      pf[s] = __builtin_bit_cast(bf16x8, f);
    }
    // PV: O^T += V^T · P^T
#pragma unroll
    for (int s = 0; s < 2; ++s)
#pragma unroll
      for (int dt = 0; dt < 4; ++dt)
        oacc[dt] = mfma16(*(const bf16x8*)(vb + (2 * dt + s) * 512 + lane * 8),
                          pf[s], oacc[dt]);

    // full drain + barrier: next tile staged, all waves done reading kv[cur]
    __syncthreads();
  }
  float inv = 1.0f / lrun;
  bf16* orow = a2 + ((size_t)(n * SEQ + q)) * EMB + h * DH;
#pragma unroll
  for (int dt = 0; dt < 4; ++dt) {
    bf16x4 w2;
#pragma unroll
    for (int r = 0; r < 4; ++r) w2[r] = (bf16)(oacc[dt][r] * inv);
    *(bf16x4*)(orow + 16 * dt + 4 * g) = w2;
  }
}

// ---------------- G: out = a2 · Wo2^T + bo (LDS-staged) --------------------
__global__ __launch_bounds__(256) void out_gemm(const bf16* __restrict__ a2,
                                                const bf16* __restrict__ wo2f,
                                                const float* __restrict__ bo,
                                                float* __restrict__ out) {
  int blk = blockIdx.x;  // mt*16 + et
  int et = blk & 15, mt = blk >> 4;
  int tid = threadIdx.x, wave = tid >> 6, lane = tid & 63;
  int g = lane >> 4, c = lane & 15;
  int m = mt * 64 + wave * 16 + c;
  const bf16* arow = a2 + (size_t)m * EMB + 8 * g;

  __shared__ bf16 wbuf[2][2048];  // 2 x 4KB k-chunks of Wo2 fragments
  const char* wtile = (const char*)wo2f + (size_t)et * 32 * 4096;
  int lofs = lane * 16, wofs = wave * 1024;

  GL16(wtile + wofs + lofs, (char*)&wbuf[0][0] + wofs);
  bf16x8 bnext = *(const bf16x8*)(arow);
  __syncthreads();

  f32x4 acc[4];
#pragma unroll
  for (int t = 0; t < 4; ++t) acc[t] = (f32x4){0.f, 0.f, 0.f, 0.f};

  for (int kc = 0; kc < 32; ++kc) {
    int cur = kc & 1;
    bf16x8 bfr = bnext;
    if (kc < 31) {
      GL16(wtile + (size_t)(kc + 1) * 4096 + wofs + lofs,
           (char*)&wbuf[cur ^ 1][0] + wofs);
      bnext = *(const bf16x8*)(arow + (kc + 1) * 32);
    }
    const bf16* wb = &wbuf[cur][0];
#pragma unroll
    for (int t = 0; t < 4; ++t)
      acc[t] = mfma16(*(const bf16x8*)(wb + t * 512 + lane * 8), bfr, acc[t]);
    __syncthreads();
  }
#pragma unroll
  for (int t = 0; t < 4; ++t) {
    int e = et * 64 + 16 * t + 4 * g;
    f32x4 b = *(const f32x4*)(bo + e);
    f32x4 w;
#pragma unroll
    for (int r = 0; r < 4; ++r) w[r] = acc[t][r] + b[r];
    *(f32x4*)(out + (size_t)m * EMB + e) = w;
  }
}

extern "C" void kernel_launch(void* const* d_in, const int* in_sizes, int n_in,
                              void* d_out, int out_size, void* d_ws, size_t ws_size,
                              hipStream_t stream) {
  const float* values = (const float*)d_in[0];
  const float* keys   = (const float*)d_in[1];
  const float* query  = (const float*)d_in[2];
  const int*   mask   = (const int*)d_in[3];
  const float* Wv     = (const float*)d_in[4];
  const float* Wk     = (const float*)d_in[5];
  const float* Wq     = (const float*)d_in[6];
  const float* Wo     = (const float*)d_in[7];
  const float* bo     = (const float*)d_in[8];

  char* ws = (char*)d_ws;
  bf16* mqk  = (bf16*)(ws + OFF_MQK);
  bf16* wo2f = (bf16*)(ws + OFF_WO2);
  bf16* k2f  = (bf16*)(ws + OFF_K2);
  bf16* vtf  = (bf16*)(ws + OFF_VT);
  bf16* a2   = (bf16*)(ws + OFF_A2);
  u64*  mb   = (u64*)(ws + OFF_MB);

  prep0<<<1, 256, 0, stream>>>(Wq, Wk, mqk);
  prep1<<<1024, 256, 0, stream>>>(Wo, Wv, wo2f);
  proj_k2<<<1024, 256, 0, stream>>>(keys, mqk, k2f);
  vtrans<<<1024, 256, 0, stream>>>(values, vtf);
  maskpack<<<32768, 256, 0, stream>>>(mask, mb);
  attn<<<1024, 256, 0, stream>>>(query, k2f, vtf, mb, a2);
  out_gemm<<<1024, 256, 0, stream>>>(a2, wo2f, bo, (float*)d_out);
}

// Round 5
// 148.325 us; speedup vs baseline: 2.5241x; 1.1395x over previous
//
#include <hip/hip_runtime.h>
#include <hip/hip_bf16.h>

#define SEQ 2048
#define NH 16
#define DH 64
#define EMB 1024

typedef __bf16 bf16;
typedef __attribute__((ext_vector_type(8))) __bf16 bf16x8;
typedef __attribute__((ext_vector_type(4))) __bf16 bf16x4;
typedef __attribute__((ext_vector_type(4))) float f32x4;
typedef __attribute__((ext_vector_type(4))) unsigned int u32x4;
typedef unsigned long long u64;

// workspace layout (bytes)
#define OFF_MQK  0                         // 64*64 bf16      = 8 KB
#define OFF_WO2  8192                      // 1024*1024 bf16  = 2 MB (fragment order)
#define OFF_K2   (8192 + 2097152)          // [N][H][32 kt][8KB frag tiles] = 8 MB
#define OFF_VT   (OFF_K2 + 8388608)        // [N][H][32 kt][8KB frag tiles] = 8 MB
#define OFF_A2   (OFF_VT + 8388608)        // [N][L][1024] bf16  = 8 MB
#define OFF_MB   (OFF_A2 + 8388608)        // [N][L][32] u64     = 1 MB

#define LOG2E 1.44269504088896340736f

__device__ __forceinline__ f32x4 mfma16(bf16x8 a, bf16x8 b, f32x4 c) {
  return __builtin_amdgcn_mfma_f32_16x16x32_bf16(a, b, c, 0, 0, 0);
}

#define GL16(g, l)                                                            \
  __builtin_amdgcn_global_load_lds(                                           \
      (const __attribute__((address_space(1))) void*)(g),                     \
      (__attribute__((address_space(3))) void*)(l), 16, 0, 0)

__device__ __forceinline__ unsigned pack_bf16(float p0, float p1) {
  unsigned short b0 = __builtin_bit_cast(unsigned short, (bf16)p0);
  unsigned short b1 = __builtin_bit_cast(unsigned short, (bf16)p1);
  return (unsigned)b0 | ((unsigned)b1 << 16);
}

// ---------------- P0: Mqk = (Wq^T Wk) * log2(e)/8, to bf16 -----------------
__global__ __launch_bounds__(256) void prep0(const float* __restrict__ Wq,
                                             const float* __restrict__ Wk,
                                             bf16* __restrict__ mqk) {
  __shared__ float wq[64 * 64];
  __shared__ float wk[64 * 64];
  int tid = threadIdx.x;
  for (int i = tid; i < 4096; i += 256) { wq[i] = Wq[i]; wk[i] = Wk[i]; }
  __syncthreads();
  for (int idx = tid; idx < 4096; idx += 256) {
    int d1 = idx >> 6, d2 = idx & 63;
    float s = 0.f;
#pragma unroll
    for (int e = 0; e < 64; ++e) s += wq[e * 64 + d1] * wk[e * 64 + d2];
    mqk[idx] = (bf16)(s * 0.125f * LOG2E);
  }
}

// ---------------- fused prep: prep1 | proj_k2 | vtrans | maskpack ----------
__global__ __launch_bounds__(256) void prep_fused(
    const float* __restrict__ Wo, const float* __restrict__ Wv,
    const float* __restrict__ keys, const bf16* __restrict__ mqk,
    const float* __restrict__ values, const int* __restrict__ mask,
    bf16* __restrict__ wo2f, bf16* __restrict__ k2f, bf16* __restrict__ vtf,
    u64* __restrict__ mb) {
  __shared__ __align__(16) float smem[5184];  // 20.7 KB shared by branches
  int blk = blockIdx.x;
  int tid = threadIdx.x;

  if (blk < 1024) {
    // ---- prep1: Wo2[e][h*64+d'] = sum_d Wo[e][h*64+d]*Wv[d][d'], frag order
    int e = blk;
    float* wv = smem;            // 4096
    float* worow = smem + 4096;  // 1024
    for (int i = tid; i < 4096; i += 256) wv[i] = Wv[i];
    for (int i = tid; i < 1024; i += 256) worow[i] = Wo[(size_t)e * 1024 + i];
    __syncthreads();
    int c0 = tid * 4;
    bf16x4 w;
#pragma unroll
    for (int j = 0; j < 4; ++j) {
      int col = c0 + j;
      int hb = col & ~63, dp = col & 63;
      float s = 0.f;
#pragma unroll
      for (int d = 0; d < 64; ++d) s += worow[hb + d] * wv[d * 64 + dp];
      w[j] = (bf16)s;
    }
    int et = e >> 6, t = (e >> 4) & 3, cc = e & 15;
    int kc = c0 >> 5, gg = (c0 >> 3) & 3, half = (c0 >> 2) & 1;
    char* dst = (char*)wo2f + ((size_t)(et * 32 + kc)) * 4096 + t * 1024 +
                (gg * 16 + cc) * 16 + 8 * half;
    *(bf16x4*)dst = w;
  } else if (blk < 2048) {
    // ---- proj_k2: K2' = k_raw @ Mqk^T, fragment order
    int b = blk - 1024;
    int lt = b & 31, h = (b >> 5) & 15, n = b >> 9;
    int wave = tid >> 6, lane = tid & 63;
    int g = lane >> 4, c = lane & 15;
    bf16x8 am[4][2];
#pragma unroll
    for (int t = 0; t < 4; ++t)
#pragma unroll
      for (int s = 0; s < 2; ++s)
        am[t][s] = *(const bf16x8*)(mqk + (16 * t + c) * 64 + 32 * s + 8 * g);
    int l = lt * 64 + wave * 16 + c;
    const float* krow = keys + ((size_t)(n * SEQ + l)) * EMB + h * DH;
    bf16x8 bfr[2];
#pragma unroll
    for (int s = 0; s < 2; ++s) {
      f32x4 x0 = *(const f32x4*)(krow + 32 * s + 8 * g);
      f32x4 x1 = *(const f32x4*)(krow + 32 * s + 8 * g + 4);
      bf16x8 t;
#pragma unroll
      for (int i = 0; i < 4; ++i) { t[i] = (bf16)x0[i]; t[4 + i] = (bf16)x1[i]; }
      bfr[s] = t;
    }
    char* tb = (char*)k2f + (size_t)((n * NH + h) * 32 + lt) * 8192 + wave * 2048;
#pragma unroll
    for (int t = 0; t < 4; ++t) {
      f32x4 a = {0.f, 0.f, 0.f, 0.f};
      a = mfma16(am[t][0], bfr[0], a);
      a = mfma16(am[t][1], bfr[1], a);
      bf16x4 w;
#pragma unroll
      for (int r = 0; r < 4; ++r) w[r] = (bf16)a[r];
      char* dst = tb + (t >> 1) * 1024 +
                  ((2 * (t & 1) + (g >> 1)) * 16 + c) * 16 + 8 * (g & 1);
      *(bf16x4*)dst = w;
    }
  } else if (blk < 3072) {
    // ---- vtrans: V^T fragment order
    int b = blk - 2048;
    int lt = b & 31, h = (b >> 5) & 15, n = b >> 9;
    float (*lds)[65] = (float(*)[65])smem;
    {
      int r = tid >> 2, cg = (tid & 3) * 16;
      const float* vrow =
          values + ((size_t)(n * SEQ + lt * 64 + r)) * EMB + h * DH + cg;
#pragma unroll
      for (int j = 0; j < 16; j += 4) {
        f32x4 x = *(const f32x4*)(vrow + j);
        lds[r][cg + j + 0] = x[0];
        lds[r][cg + j + 1] = x[1];
        lds[r][cg + j + 2] = x[2];
        lds[r][cg + j + 3] = x[3];
      }
    }
    __syncthreads();
    {
      int d = tid >> 2, q16 = tid & 3, lb = q16 * 16;
      bf16x8 w0, w1;
#pragma unroll
      for (int j = 0; j < 8; ++j) w0[j] = (bf16)lds[lb + j][d];
#pragma unroll
      for (int j = 0; j < 8; ++j) w1[j] = (bf16)lds[lb + 8 + j][d];
      int dt = d >> 4, cc = d & 15;
      int s = q16 >> 1, gg = 2 * (q16 & 1);
      char* base = (char*)vtf + (size_t)((n * NH + h) * 32 + lt) * 8192 +
                   (2 * dt + s) * 1024;
      *(bf16x8*)(base + (gg * 16 + cc) * 16) = w0;
      *(bf16x8*)(base + ((gg + 1) * 16 + cc) * 16) = w1;
    }
  } else {
    // ---- maskpack (grid-stride): mb[w] = bits of mask[w*64 .. +63]
    int base = (blk - 3072) * 4 + (tid >> 6);
    int lane = tid & 63;
#pragma unroll
    for (int i = 0; i < 16; ++i) {
      int w = base + i * 8192;
      int v = mask[(size_t)w * 64 + lane];
      u64 bbits = __ballot(v != 0);
      if (lane == 0) mb[w] = bbits;
    }
  }
}

// ---------------- F: flash attention — 2 waves x 32q, log2-domain softmax --
__global__ __launch_bounds__(128) void attn(const float* __restrict__ qraw,
                                            const bf16* __restrict__ k2f,
                                            const bf16* __restrict__ vtf,
                                            const u64* __restrict__ mb,
                                            bf16* __restrict__ a2) {
  int blk = blockIdx.x;  // n*NH*32 + h*32 + qt
  int qt = blk & 31, h = (blk >> 5) & 15, n = blk >> 9;
  int tid = threadIdx.x, wave = tid >> 6, lane = tid & 63;
  int g = lane >> 4, c = lane & 15;

  __shared__ bf16 kv[2][8192];  // [buf][K 8KB | V 8KB]
  __shared__ u64 lutm[16];      // nibble -> packed-pair AND masks
  if (tid < 16) {
    unsigned a = (tid & 1 ? 0xFFFFu : 0u) | (tid & 2 ? 0xFFFF0000u : 0u);
    unsigned b = (tid & 4 ? 0xFFFFu : 0u) | (tid & 8 ? 0xFFFF0000u : 0u);
    lutm[tid] = (u64)a | ((u64)b << 32);
  }

  // Q fragments: per qi, lane holds q=..+c, d = 32s+8g+i
  bf16x8 qf[2][2];
  const u64* mrow[2];
#pragma unroll
  for (int qi = 0; qi < 2; ++qi) {
    int q = qt * 64 + wave * 32 + qi * 16 + c;
    const float* qrow = qraw + ((size_t)(n * SEQ + q)) * EMB + h * DH;
#pragma unroll
    for (int s = 0; s < 2; ++s) {
      f32x4 x0 = *(const f32x4*)(qrow + 32 * s + 8 * g);
      f32x4 x1 = *(const f32x4*)(qrow + 32 * s + 8 * g + 4);
      bf16x8 t;
#pragma unroll
      for (int i = 0; i < 4; ++i) { t[i] = (bf16)x0[i]; t[4 + i] = (bf16)x1[i]; }
      qf[qi][s] = t;
    }
    mrow[qi] = mb + ((size_t)(n * SEQ + q)) * 32;
  }
  const char* kbase = (const char*)k2f + (size_t)(n * NH + h) * 32 * 8192;
  const char* vbase = (const char*)vtf + (size_t)(n * NH + h) * 32 * 8192;

  int lofs = lane * 16, wofs = wave * 1024;
  // stage one 16KB K|V tile (8 x GL16, wave-uniform LDS dest)
#define STAGE(KT, BUF)                                                        \
  {                                                                           \
    char* lb_ = (char*)&kv[BUF][0] + wofs;                                    \
    const char* kg_ = kbase + (size_t)(KT) * 8192 + wofs + lofs;              \
    const char* vg_ = vbase + (size_t)(KT) * 8192 + wofs + lofs;              \
    GL16(kg_, lb_);                                                           \
    GL16(kg_ + 2048, lb_ + 2048);                                             \
    GL16(kg_ + 4096, lb_ + 4096);                                             \
    GL16(kg_ + 6144, lb_ + 6144);                                             \
    GL16(vg_, lb_ + 8192);                                                    \
    GL16(vg_ + 2048, lb_ + 10240);                                            \
    GL16(vg_ + 4096, lb_ + 12288);                                            \
    GL16(vg_ + 6144, lb_ + 14336);                                            \
  }

  STAGE(0, 0);
  u64 mwn0 = mrow[0][0], mwn1 = mrow[1][0];
  __syncthreads();

  f32x4 oacc[2][4];
#pragma unroll
  for (int qi = 0; qi < 2; ++qi)
#pragma unroll
    for (int dt = 0; dt < 4; ++dt) oacc[qi][dt] = (f32x4){0.f, 0.f, 0.f, 0.f};
  float mrun[2] = {-1e30f, -1e30f}, lrun[2] = {0.f, 0.f};
  bf16x8 ones;
#pragma unroll
  for (int i = 0; i < 8; ++i) ones[i] = (bf16)1.0f;
  int sh0 = 4 * g, sh1 = sh0 + 16;
  int srcA = ((g & 1) << 5) | c;
  int srcB = srcA + 16;
  bool hi2 = (g >> 1) != 0;

  for (int kt = 0; kt < 32; ++kt) {
    int cur = kt & 1;
    u64 mw[2] = {mwn0, mwn1};
    if (kt < 31) {
      STAGE(kt + 1, cur ^ 1);
      mwn0 = mrow[0][kt + 1];
      mwn1 = mrow[1][kt + 1];
    }
    const bf16* kb = &kv[cur][0];
    const bf16* vb = &kv[cur][4096];

    // QK^T (both qi share K fragments): lane(g,c): q=c, kk=16t+4g+r
    f32x4 sacc[2][4];
#pragma unroll
    for (int t = 0; t < 4; ++t) {
      bf16x8 k0 = *(const bf16x8*)(kb + (2 * t) * 512 + lane * 8);
      bf16x8 k1 = *(const bf16x8*)(kb + (2 * t + 1) * 512 + lane * 8);
#pragma unroll
      for (int qi = 0; qi < 2; ++qi) {
        f32x4 a = {0.f, 0.f, 0.f, 0.f};
        a = mfma16(k0, qf[qi][0], a);
        a = mfma16(k1, qf[qi][1], a);
        sacc[qi][t] = a;
      }
    }
    // raw (unmasked) row max — safe: m >= needed, masked p's zeroed later
    float tmax[2];
#pragma unroll
    for (int qi = 0; qi < 2; ++qi) {
      float a0 = fmaxf(fmaxf(sacc[qi][0][0], sacc[qi][0][1]),
                       fmaxf(sacc[qi][0][2], sacc[qi][0][3]));
      float a1 = fmaxf(fmaxf(sacc[qi][1][0], sacc[qi][1][1]),
                       fmaxf(sacc[qi][1][2], sacc[qi][1][3]));
      float a2_ = fmaxf(fmaxf(sacc[qi][2][0], sacc[qi][2][1]),
                        fmaxf(sacc[qi][2][2], sacc[qi][2][3]));
      float a3 = fmaxf(fmaxf(sacc[qi][3][0], sacc[qi][3][1]),
                       fmaxf(sacc[qi][3][2], sacc[qi][3][3]));
      float m = fmaxf(fmaxf(a0, a1), fmaxf(a2_, a3));
      m = fmaxf(m, __shfl_xor(m, 16));
      m = fmaxf(m, __shfl_xor(m, 32));
      tmax[qi] = m;
    }
    // defer-max: rescale only when max grew by > 8 (log2 units)
    bool needs = (tmax[0] > mrun[0] + 8.f) || (tmax[1] > mrun[1] + 8.f);
    if (__any(needs)) {
#pragma unroll
      for (int qi = 0; qi < 2; ++qi) {
        float mnew = fmaxf(mrun[qi], tmax[qi]);
        float scl = __builtin_amdgcn_exp2f(mrun[qi] - mnew);
        lrun[qi] *= scl;
#pragma unroll
        for (int dt = 0; dt < 4; ++dt) {
          oacc[qi][dt][0] *= scl; oacc[qi][dt][1] *= scl;
          oacc[qi][dt][2] *= scl; oacc[qi][dt][3] *= scl;
        }
        mrun[qi] = mnew;
      }
    }
    // p = 2^(s - m), pack to bf16 pairs, mask via LUT-AND
    unsigned wpk[2][4][2];
#pragma unroll
    for (int qi = 0; qi < 2; ++qi) {
      unsigned mlo = (unsigned)mw[qi], mhi = (unsigned)(mw[qi] >> 32);
      u64 L[4];
      L[0] = lutm[(mlo >> sh0) & 15];
      L[1] = lutm[(mlo >> sh1) & 15];
      L[2] = lutm[(mhi >> sh0) & 15];
      L[3] = lutm[(mhi >> sh1) & 15];
      float mr = mrun[qi];
#pragma unroll
      for (int t = 0; t < 4; ++t) {
        float p0 = __builtin_amdgcn_exp2f(sacc[qi][t][0] - mr);
        float p1 = __builtin_amdgcn_exp2f(sacc[qi][t][1] - mr);
        float p2 = __builtin_amdgcn_exp2f(sacc[qi][t][2] - mr);
        float p3 = __builtin_amdgcn_exp2f(sacc[qi][t][3] - mr);
        wpk[qi][t][0] = pack_bf16(p0, p1) & (unsigned)L[t];
        wpk[qi][t][1] = pack_bf16(p2, p3) & (unsigned)(L[t] >> 32);
      }
    }
    // P fragments via shuffles (verified mapping): dest lane(g,c) frag s
    // needs kk=32s+8g+i for q=c; sources lanes srcA/srcB, word 2s+(g>>1)
    bf16x8 pf[2][2];
#pragma unroll
    for (int qi = 0; qi < 2; ++qi)
#pragma unroll
      for (int s = 0; s < 2; ++s) {
        unsigned ta0 = (unsigned)__shfl((int)wpk[qi][2 * s][0], srcA);
        unsigned ta1 = (unsigned)__shfl((int)wpk[qi][2 * s][1], srcA);
        unsigned tb0 = (unsigned)__shfl((int)wpk[qi][2 * s + 1][0], srcA);
        unsigned tb1 = (unsigned)__shfl((int)wpk[qi][2 * s + 1][1], srcA);
        unsigned ua0 = (unsigned)__shfl((int)wpk[qi][2 * s][0], srcB);
        unsigned ua1 = (unsigned)__shfl((int)wpk[qi][2 * s][1], srcB);
        unsigned ub0 = (unsigned)__shfl((int)wpk[qi][2 * s + 1][0], srcB);
        unsigned ub1 = (unsigned)__shfl((int)wpk[qi][2 * s + 1][1], srcB);
        u32x4 f;
        f[0] = hi2 ? tb0 : ta0;
        f[1] = hi2 ? tb1 : ta1;
        f[2] = hi2 ? ub0 : ua0;
        f[3] = hi2 ? ub1 : ua1;
        pf[qi][s] = __builtin_bit_cast(bf16x8, f);
      }
    // psum via ones-MFMA on masked P: D[i][c] = sum_kk P[c][kk] (all i equal)
    f32x4 pacc[2];
#pragma unroll
    for (int qi = 0; qi < 2; ++qi) {
      f32x4 a = {0.f, 0.f, 0.f, 0.f};
      a = mfma16(ones, pf[qi][0], a);
      a = mfma16(ones, pf[qi][1], a);
      pacc[qi] = a;
    }
    // PV: O^T += V^T · P^T (both qi share V fragments)
#pragma unroll
    for (int dt = 0; dt < 4; ++dt)
#pragma unroll
      for (int s = 0; s < 2; ++s) {
        bf16x8 vf = *(const bf16x8*)(vb + (2 * dt + s) * 512 + lane * 8);
#pragma unroll
        for (int qi = 0; qi < 2; ++qi)
          oacc[qi][dt] = mfma16(vf, pf[qi][s], oacc[qi][dt]);
      }
#pragma unroll
    for (int qi = 0; qi < 2; ++qi) lrun[qi] += pacc[qi][0];

    __syncthreads();  // next tile staged; all waves done with kv[cur]
  }
#pragma unroll
  for (int qi = 0; qi < 2; ++qi) {
    float inv = 1.0f / lrun[qi];
    int q = qt * 64 + wave * 32 + qi * 16 + c;
    bf16* orow = a2 + ((size_t)(n * SEQ + q)) * EMB + h * DH;
#pragma unroll
    for (int dt = 0; dt < 4; ++dt) {
      bf16x4 w2;
#pragma unroll
      for (int r = 0; r < 4; ++r) w2[r] = (bf16)(oacc[qi][dt][r] * inv);
      *(bf16x4*)(orow + 16 * dt + 4 * g) = w2;
    }
  }
}

// ---------------- G: out = a2 · Wo2^T + bo (LDS-staged, BK=64) -------------
__global__ __launch_bounds__(256) void out_gemm(const bf16* __restrict__ a2,
                                                const bf16* __restrict__ wo2f,
                                                const float* __restrict__ bo,
                                                float* __restrict__ out) {
  int blk = blockIdx.x;  // mt*16 + et
  int et = blk & 15, mt = blk >> 4;
  int tid = threadIdx.x, wave = tid >> 6, lane = tid & 63;
  int g = lane >> 4, c = lane & 15;
  int m = mt * 64 + wave * 16 + c;
  const bf16* arow = a2 + (size_t)m * EMB + 8 * g;

  __shared__ bf16 wbuf[2][4096];  // 2 x 8KB (two 4KB kc-chunks each)
  const char* wtile = (const char*)wo2f + (size_t)et * 32 * 4096;
  int lofs = lane * 16, wofs = wave * 1024;

#define STAGEW(J, BUF)                                                        \
  {                                                                           \
    const char* src_ = wtile + (size_t)(J) * 8192 + wofs + lofs;              \
    char* dst_ = (char*)&wbuf[BUF][0] + wofs;                                 \
    GL16(src_, dst_);                                                         \
    GL16(src_ + 4096, dst_ + 4096);                                           \
  }

  STAGEW(0, 0);
  bf16x8 bn0 = *(const bf16x8*)(arow);
  bf16x8 bn1 = *(const bf16x8*)(arow + 32);
  __syncthreads();

  f32x4 acc[4];
#pragma unroll
  for (int t = 0; t < 4; ++t) acc[t] = (f32x4){0.f, 0.f, 0.f, 0.f};

  for (int j = 0; j < 16; ++j) {
    int cur = j & 1;
    bf16x8 b0 = bn0, b1 = bn1;
    if (j < 15) {
      STAGEW(j + 1, cur ^ 1);
      bn0 = *(const bf16x8*)(arow + (j + 1) * 64);
      bn1 = *(const bf16x8*)(arow + (j + 1) * 64 + 32);
    }
    const bf16* wb = &wbuf[cur][0];
#pragma unroll
    for (int t = 0; t < 4; ++t)
      acc[t] = mfma16(*(const bf16x8*)(wb + t * 512 + lane * 8), b0, acc[t]);
#pragma unroll
    for (int t = 0; t < 4; ++t)
      acc[t] =
          mfma16(*(const bf16x8*)(wb + 2048 + t * 512 + lane * 8), b1, acc[t]);
    __syncthreads();
  }
#pragma unroll
  for (int t = 0; t < 4; ++t) {
    int e = et * 64 + 16 * t + 4 * g;
    f32x4 b = *(const f32x4*)(bo + e);
    f32x4 w;
#pragma unroll
    for (int r = 0; r < 4; ++r) w[r] = acc[t][r] + b[r];
    *(f32x4*)(out + (size_t)m * EMB + e) = w;
  }
}

extern "C" void kernel_launch(void* const* d_in, const int* in_sizes, int n_in,
                              void* d_out, int out_size, void* d_ws, size_t ws_size,
                              hipStream_t stream) {
  const float* values = (const float*)d_in[0];
  const float* keys   = (const float*)d_in[1];
  const float* query  = (const float*)d_in[2];
  const int*   mask   = (const int*)d_in[3];
  const float* Wv     = (const float*)d_in[4];
  const float* Wk     = (const float*)d_in[5];
  const float* Wq     = (const float*)d_in[6];
  const float* Wo     = (const float*)d_in[7];
  const float* bo     = (const float*)d_in[8];

  char* ws = (char*)d_ws;
  bf16* mqk  = (bf16*)(ws + OFF_MQK);
  bf16* wo2f = (bf16*)(ws + OFF_WO2);
  bf16* k2f  = (bf16*)(ws + OFF_K2);
  bf16* vtf  = (bf16*)(ws + OFF_VT);
  bf16* a2   = (bf16*)(ws + OFF_A2);
  u64*  mb   = (u64*)(ws + OFF_MB);

  prep0<<<1, 256, 0, stream>>>(Wq, Wk, mqk);
  prep_fused<<<5120, 256, 0, stream>>>(Wo, Wv, keys, mqk, values, mask,
                                       wo2f, k2f, vtf, mb);
  attn<<<1024, 128, 0, stream>>>(query, k2f, vtf, mb, a2);
  out_gemm<<<1024, 256, 0, stream>>>(a2, wo2f, bo, (float*)d_out);
}

// Round 6
// 126.133 us; speedup vs baseline: 2.9682x; 1.1759x over previous
//
#include <hip/hip_runtime.h>
#include <hip/hip_bf16.h>

#define SEQ 2048
#define NH 16
#define DH 64
#define EMB 1024

typedef __bf16 bf16;
typedef __attribute__((ext_vector_type(8))) __bf16 bf16x8;
typedef __attribute__((ext_vector_type(4))) __bf16 bf16x4;
typedef __attribute__((ext_vector_type(4))) float f32x4;
typedef __attribute__((ext_vector_type(4))) unsigned int u32x4;
typedef unsigned long long u64;

// workspace layout (bytes)
#define OFF_MQK  0                         // 64*64 bf16      = 8 KB
#define OFF_WO2  8192                      // 1024*1024 bf16  = 2 MB (fragment order)
#define OFF_K2   (8192 + 2097152)          // [N][H][32 kt][8KB frag tiles] = 8 MB
#define OFF_VT   (OFF_K2 + 8388608)        // [N][H][32 kt][8KB frag tiles] = 8 MB
#define OFF_A2   (OFF_VT + 8388608)        // [N][L][1024] bf16  = 8 MB
#define OFF_MB   (OFF_A2 + 8388608)        // mbt[N][32 kt][2048 q] u64 = 1 MB

#define LOG2E 1.44269504088896340736f

__device__ __forceinline__ f32x4 mfma16(bf16x8 a, bf16x8 b, f32x4 c) {
  return __builtin_amdgcn_mfma_f32_16x16x32_bf16(a, b, c, 0, 0, 0);
}

#define GL16(g, l)                                                            \
  __builtin_amdgcn_global_load_lds(                                           \
      (const __attribute__((address_space(1))) void*)(g),                     \
      (__attribute__((address_space(3))) void*)(l), 16, 0, 0)

__device__ __forceinline__ unsigned pack_bf16(float p0, float p1) {
  unsigned short b0 = __builtin_bit_cast(unsigned short, (bf16)p0);
  unsigned short b1 = __builtin_bit_cast(unsigned short, (bf16)p1);
  return (unsigned)b0 | ((unsigned)b1 << 16);
}

// ---------------- P0: Mqk = (Wq^T Wk) * log2(e)/8, to bf16 -----------------
__global__ __launch_bounds__(256) void prep0(const float* __restrict__ Wq,
                                             const float* __restrict__ Wk,
                                             bf16* __restrict__ mqk) {
  __shared__ float wq[64 * 64];
  __shared__ float wk[64 * 64];
  int tid = threadIdx.x;
  for (int i = tid; i < 4096; i += 256) { wq[i] = Wq[i]; wk[i] = Wk[i]; }
  __syncthreads();
  for (int idx = tid; idx < 4096; idx += 256) {
    int d1 = idx >> 6, d2 = idx & 63;
    float s = 0.f;
#pragma unroll
    for (int e = 0; e < 64; ++e) s += wq[e * 64 + d1] * wk[e * 64 + d2];
    mqk[idx] = (bf16)(s * 0.125f * LOG2E);
  }
}

// ---------------- fused prep: prep1 | proj_k2 | vtrans | maskpack ----------
__global__ __launch_bounds__(256) void prep_fused(
    const float* __restrict__ Wo, const float* __restrict__ Wv,
    const float* __restrict__ keys, const bf16* __restrict__ mqk,
    const float* __restrict__ values, const int* __restrict__ mask,
    bf16* __restrict__ wo2f, bf16* __restrict__ k2f, bf16* __restrict__ vtf,
    u64* __restrict__ mbt) {
  __shared__ __align__(16) float smem[5184];  // 20.7 KB shared by branches
  int blk = blockIdx.x;
  int tid = threadIdx.x;

  if (blk < 1024) {
    // ---- prep1: Wo2[e][h*64+d'] = sum_d Wo[e][h*64+d]*Wv[d][d'], frag order
    int e = blk;
    float* wv = smem;            // 4096
    float* worow = smem + 4096;  // 1024
    for (int i = tid; i < 4096; i += 256) wv[i] = Wv[i];
    for (int i = tid; i < 1024; i += 256) worow[i] = Wo[(size_t)e * 1024 + i];
    __syncthreads();
    int c0 = tid * 4;
    bf16x4 w;
#pragma unroll
    for (int j = 0; j < 4; ++j) {
      int col = c0 + j;
      int hb = col & ~63, dp = col & 63;
      float s = 0.f;
#pragma unroll
      for (int d = 0; d < 64; ++d) s += worow[hb + d] * wv[d * 64 + dp];
      w[j] = (bf16)s;
    }
    int et = e >> 6, t = (e >> 4) & 3, cc = e & 15;
    int kc = c0 >> 5, gg = (c0 >> 3) & 3, half = (c0 >> 2) & 1;
    char* dst = (char*)wo2f + ((size_t)(et * 32 + kc)) * 4096 + t * 1024 +
                (gg * 16 + cc) * 16 + 8 * half;
    *(bf16x4*)dst = w;
  } else if (blk < 2048) {
    // ---- proj_k2: K2' = k_raw @ Mqk^T, fragment order
    int b = blk - 1024;
    int lt = b & 31, h = (b >> 5) & 15, n = b >> 9;
    int wave = tid >> 6, lane = tid & 63;
    int g = lane >> 4, c = lane & 15;
    bf16x8 am[4][2];
#pragma unroll
    for (int t = 0; t < 4; ++t)
#pragma unroll
      for (int s = 0; s < 2; ++s)
        am[t][s] = *(const bf16x8*)(mqk + (16 * t + c) * 64 + 32 * s + 8 * g);
    int l = lt * 64 + wave * 16 + c;
    const float* krow = keys + ((size_t)(n * SEQ + l)) * EMB + h * DH;
    bf16x8 bfr[2];
#pragma unroll
    for (int s = 0; s < 2; ++s) {
      f32x4 x0 = *(const f32x4*)(krow + 32 * s + 8 * g);
      f32x4 x1 = *(const f32x4*)(krow + 32 * s + 8 * g + 4);
      bf16x8 t;
#pragma unroll
      for (int i = 0; i < 4; ++i) { t[i] = (bf16)x0[i]; t[4 + i] = (bf16)x1[i]; }
      bfr[s] = t;
    }
    char* tb = (char*)k2f + (size_t)((n * NH + h) * 32 + lt) * 8192 + wave * 2048;
#pragma unroll
    for (int t = 0; t < 4; ++t) {
      f32x4 a = {0.f, 0.f, 0.f, 0.f};
      a = mfma16(am[t][0], bfr[0], a);
      a = mfma16(am[t][1], bfr[1], a);
      bf16x4 w;
#pragma unroll
      for (int r = 0; r < 4; ++r) w[r] = (bf16)a[r];
      char* dst = tb + (t >> 1) * 1024 +
                  ((2 * (t & 1) + (g >> 1)) * 16 + c) * 16 + 8 * (g & 1);
      *(bf16x4*)dst = w;
    }
  } else if (blk < 3072) {
    // ---- vtrans: V^T fragment order
    int b = blk - 2048;
    int lt = b & 31, h = (b >> 5) & 15, n = b >> 9;
    float (*lds)[65] = (float(*)[65])smem;
    {
      int r = tid >> 2, cg = (tid & 3) * 16;
      const float* vrow =
          values + ((size_t)(n * SEQ + lt * 64 + r)) * EMB + h * DH + cg;
#pragma unroll
      for (int j = 0; j < 16; j += 4) {
        f32x4 x = *(const f32x4*)(vrow + j);
        lds[r][cg + j + 0] = x[0];
        lds[r][cg + j + 1] = x[1];
        lds[r][cg + j + 2] = x[2];
        lds[r][cg + j + 3] = x[3];
      }
    }
    __syncthreads();
    {
      int d = tid >> 2, q16 = tid & 3, lb = q16 * 16;
      bf16x8 w0, w1;
#pragma unroll
      for (int j = 0; j < 8; ++j) w0[j] = (bf16)lds[lb + j][d];
#pragma unroll
      for (int j = 0; j < 8; ++j) w1[j] = (bf16)lds[lb + 8 + j][d];
      int dt = d >> 4, cc = d & 15;
      int s = q16 >> 1, gg = 2 * (q16 & 1);
      char* base = (char*)vtf + (size_t)((n * NH + h) * 32 + lt) * 8192 +
                   (2 * dt + s) * 1024;
      *(bf16x8*)(base + (gg * 16 + cc) * 16) = w0;
      *(bf16x8*)(base + ((gg + 1) * 16 + cc) * 16) = w1;
    }
  } else {
    // ---- maskpack (grid-stride), TRANSPOSED: mbt[n][kw][q]
    int base = (blk - 3072) * 4 + (tid >> 6);
    int lane = tid & 63;
#pragma unroll
    for (int i = 0; i < 16; ++i) {
      int w = base + i * 8192;  // w = (n*2048 + q)*32 + kw
      int v = mask[(size_t)w * 64 + lane];
      u64 bbits = __ballot(v != 0);
      int kw = w & 31, q = (w >> 5) & 2047, nn = w >> 16;
      if (lane == 0) mbt[((size_t)nn * 32 + kw) * 2048 + q] = bbits;
    }
  }
}

// ---------------- F: flash attention — 1 wave/block, all-register K/V ------
__global__ __launch_bounds__(64, 2) void attn(const float* __restrict__ qraw,
                                              const bf16* __restrict__ k2f,
                                              const bf16* __restrict__ vtf,
                                              const u64* __restrict__ mbt,
                                              bf16* __restrict__ a2) {
  // bijective XCD swizzle: 2048 blocks, 256 per XCD -> ~4 (n,h) per XCD L2
  int swz = ((blockIdx.x & 7) << 8) | (blockIdx.x >> 3);
  int qt = swz & 63, h = (swz >> 6) & 15, n = swz >> 10;  // qt: 32-row tile
  int lane = threadIdx.x, g = lane >> 4, c = lane & 15;

  __shared__ u64 lutm[16];  // nibble -> packed-pair AND masks
  if (lane < 16) {
    unsigned a = (lane & 1 ? 0xFFFFu : 0u) | (lane & 2 ? 0xFFFF0000u : 0u);
    unsigned b = (lane & 4 ? 0xFFFFu : 0u) | (lane & 8 ? 0xFFFF0000u : 0u);
    lutm[lane] = (u64)a | ((u64)b << 32);
  }
  __syncthreads();

  // Q fragments: per qi, lane holds q = qt*32 + qi*16 + c, d = 32s+8g+i
  bf16x8 qf[2][2];
#pragma unroll
  for (int qi = 0; qi < 2; ++qi) {
    int q = qt * 32 + qi * 16 + c;
    const float* qrow = qraw + ((size_t)(n * SEQ + q)) * EMB + h * DH;
#pragma unroll
    for (int s = 0; s < 2; ++s) {
      f32x4 x0 = *(const f32x4*)(qrow + 32 * s + 8 * g);
      f32x4 x1 = *(const f32x4*)(qrow + 32 * s + 8 * g + 4);
      bf16x8 t;
#pragma unroll
      for (int i = 0; i < 4; ++i) { t[i] = (bf16)x0[i]; t[4 + i] = (bf16)x1[i]; }
      qf[qi][s] = t;
    }
  }
  const char* kp = (const char*)k2f + (size_t)(n * NH + h) * 32 * 8192 + lane * 16;
  const char* vp = (const char*)vtf + (size_t)(n * NH + h) * 32 * 8192 + lane * 16;
  const u64* mq = mbt + (size_t)n * 32 * 2048 + qt * 32 + c;  // +kt*2048+qi*16

  // K(0) into registers (8 coalesced 1KB chunks)
  bf16x8 K[8], Vv[8];
#pragma unroll
  for (int j = 0; j < 8; ++j) K[j] = *(const bf16x8*)(kp + j * 1024);

  f32x4 oacc[2][4];
#pragma unroll
  for (int qi = 0; qi < 2; ++qi)
#pragma unroll
    for (int dt = 0; dt < 4; ++dt) oacc[qi][dt] = (f32x4){0.f, 0.f, 0.f, 0.f};
  float mrun[2] = {-1e30f, -1e30f}, lrun[2] = {0.f, 0.f};
  bf16x8 ones;
#pragma unroll
  for (int i = 0; i < 8; ++i) ones[i] = (bf16)1.0f;
  int sh0 = 4 * g, sh1 = sh0 + 16;
  int srcA = ((g & 1) << 5) | c;
  int srcB = srcA + 16;
  bool hi2 = (g >> 1) != 0;

  for (int kt = 0; kt < 32; ++kt) {
    // issue V(kt) early — consumed after softmax (~500 cyc later)
#pragma unroll
    for (int j = 0; j < 8; ++j)
      Vv[j] = *(const bf16x8*)(vp + (size_t)kt * 8192 + j * 1024);
    u64 mw0 = mq[kt * 2048];
    u64 mw1 = mq[kt * 2048 + 16];

    // QK^T from K regs: lane(g,c): q=c, kk=16t+4g+r
    f32x4 sacc[2][4];
#pragma unroll
    for (int t = 0; t < 4; ++t) {
      bf16x8 k0 = K[2 * t], k1 = K[2 * t + 1];
#pragma unroll
      for (int qi = 0; qi < 2; ++qi) {
        f32x4 a = {0.f, 0.f, 0.f, 0.f};
        a = mfma16(k0, qf[qi][0], a);
        a = mfma16(k1, qf[qi][1], a);
        sacc[qi][t] = a;
      }
    }
    // prefetch K(kt+1) — K regs free after the MFMAs above; latency hides
    // under softmax+PV (kt=31 reads 8KB past tile 31: valid ws, unused)
#pragma unroll
    for (int j = 0; j < 8; ++j)
      K[j] = *(const bf16x8*)(kp + (size_t)(kt + 1) * 8192 + j * 1024);

    // unmasked row max (max3-friendly triplets), reduce over g via shfl
    float tmax[2];
#pragma unroll
    for (int qi = 0; qi < 2; ++qi) {
      float x0 = sacc[qi][0][0], x1 = sacc[qi][0][1], x2 = sacc[qi][0][2],
            x3 = sacc[qi][0][3], x4 = sacc[qi][1][0], x5 = sacc[qi][1][1],
            x6 = sacc[qi][1][2], x7 = sacc[qi][1][3], x8 = sacc[qi][2][0],
            x9 = sacc[qi][2][1], xa = sacc[qi][2][2], xb = sacc[qi][2][3],
            xc = sacc[qi][3][0], xd = sacc[qi][3][1], xe = sacc[qi][3][2],
            xf = sacc[qi][3][3];
      float t0 = fmaxf(fmaxf(x0, x1), x2);
      float t1 = fmaxf(fmaxf(x3, x4), x5);
      float t2 = fmaxf(fmaxf(x6, x7), x8);
      float t3 = fmaxf(fmaxf(x9, xa), xb);
      float t4 = fmaxf(fmaxf(xc, xd), xe);
      float m = fmaxf(fmaxf(fmaxf(t0, t1), t2), fmaxf(fmaxf(t3, t4), xf));
      m = fmaxf(m, __shfl_xor(m, 16));
      m = fmaxf(m, __shfl_xor(m, 32));
      tmax[qi] = m;
    }
    // defer-max: rescale only when max grew by > 8 (log2 units)
    bool needs = (tmax[0] > mrun[0] + 8.f) || (tmax[1] > mrun[1] + 8.f);
    if (__any(needs)) {
#pragma unroll
      for (int qi = 0; qi < 2; ++qi) {
        float mnew = fmaxf(mrun[qi], tmax[qi]);
        float scl = __builtin_amdgcn_exp2f(mrun[qi] - mnew);
        lrun[qi] *= scl;
#pragma unroll
        for (int dt = 0; dt < 4; ++dt) {
          oacc[qi][dt][0] *= scl; oacc[qi][dt][1] *= scl;
          oacc[qi][dt][2] *= scl; oacc[qi][dt][3] *= scl;
        }
        mrun[qi] = mnew;
      }
    }
    // p = 2^(s-m) in bf16 pairs, mask via LUT-AND
    unsigned wpk[2][4][2];
    u64 mwa[2] = {mw0, mw1};
#pragma unroll
    for (int qi = 0; qi < 2; ++qi) {
      unsigned mlo = (unsigned)mwa[qi], mhi = (unsigned)(mwa[qi] >> 32);
      u64 L[4];
      L[0] = lutm[(mlo >> sh0) & 15];
      L[1] = lutm[(mlo >> sh1) & 15];
      L[2] = lutm[(mhi >> sh0) & 15];
      L[3] = lutm[(mhi >> sh1) & 15];
      float mr = mrun[qi];
#pragma unroll
      for (int t = 0; t < 4; ++t) {
        float p0 = __builtin_amdgcn_exp2f(sacc[qi][t][0] - mr);
        float p1 = __builtin_amdgcn_exp2f(sacc[qi][t][1] - mr);
        float p2 = __builtin_amdgcn_exp2f(sacc[qi][t][2] - mr);
        float p3 = __builtin_amdgcn_exp2f(sacc[qi][t][3] - mr);
        wpk[qi][t][0] = pack_bf16(p0, p1) & (unsigned)L[t];
        wpk[qi][t][1] = pack_bf16(p2, p3) & (unsigned)(L[t] >> 32);
      }
    }
    // P fragments via shuffles (verified): dest lane(g,c) frag s needs
    // kk=32s+8g+i for q=c; sources lanes srcA/srcB, word 2s+(g>>1)
    bf16x8 pf[2][2];
#pragma unroll
    for (int qi = 0; qi < 2; ++qi)
#pragma unroll
      for (int s = 0; s < 2; ++s) {
        unsigned ta0 = (unsigned)__shfl((int)wpk[qi][2 * s][0], srcA);
        unsigned ta1 = (unsigned)__shfl((int)wpk[qi][2 * s][1], srcA);
        unsigned tb0 = (unsigned)__shfl((int)wpk[qi][2 * s + 1][0], srcA);
        unsigned tb1 = (unsigned)__shfl((int)wpk[qi][2 * s + 1][1], srcA);
        unsigned ua0 = (unsigned)__shfl((int)wpk[qi][2 * s][0], srcB);
        unsigned ua1 = (unsigned)__shfl((int)wpk[qi][2 * s][1], srcB);
        unsigned ub0 = (unsigned)__shfl((int)wpk[qi][2 * s + 1][0], srcB);
        unsigned ub1 = (unsigned)__shfl((int)wpk[qi][2 * s + 1][1], srcB);
        u32x4 f;
        f[0] = hi2 ? tb0 : ta0;
        f[1] = hi2 ? tb1 : ta1;
        f[2] = hi2 ? ub0 : ua0;
        f[3] = hi2 ? ub1 : ua1;
        pf[qi][s] = __builtin_bit_cast(bf16x8, f);
      }
    // psum via ones-MFMA on masked P
    f32x4 pacc[2];
#pragma unroll
    for (int qi = 0; qi < 2; ++qi) {
      f32x4 a = {0.f, 0.f, 0.f, 0.f};
      a = mfma16(ones, pf[qi][0], a);
      a = mfma16(ones, pf[qi][1], a);
      pacc[qi] = a;
    }
    // PV from V regs: O^T += V^T · P^T
#pragma unroll
    for (int dt = 0; dt < 4; ++dt)
#pragma unroll
      for (int s = 0; s < 2; ++s) {
        bf16x8 vf = Vv[2 * dt + s];
#pragma unroll
        for (int qi = 0; qi < 2; ++qi)
          oacc[qi][dt] = mfma16(vf, pf[qi][s], oacc[qi][dt]);
      }
#pragma unroll
    for (int qi = 0; qi < 2; ++qi) lrun[qi] += pacc[qi][0];
  }
#pragma unroll
  for (int qi = 0; qi < 2; ++qi) {
    float inv = 1.0f / lrun[qi];
    int q = qt * 32 + qi * 16 + c;
    bf16* orow = a2 + ((size_t)(n * SEQ + q)) * EMB + h * DH;
#pragma unroll
    for (int dt = 0; dt < 4; ++dt) {
      bf16x4 w2;
#pragma unroll
      for (int r = 0; r < 4; ++r) w2[r] = (bf16)(oacc[qi][dt][r] * inv);
      *(bf16x4*)(orow + 16 * dt + 4 * g) = w2;
    }
  }
}

// ---------------- G: out = a2 · Wo2^T + bo (LDS-staged, BK=64) -------------
__global__ __launch_bounds__(256) void out_gemm(const bf16* __restrict__ a2,
                                                const bf16* __restrict__ wo2f,
                                                const float* __restrict__ bo,
                                                float* __restrict__ out) {
  int blk = blockIdx.x;  // mt*16 + et
  int et = blk & 15, mt = blk >> 4;
  int tid = threadIdx.x, wave = tid >> 6, lane = tid & 63;
  int g = lane >> 4, c = lane & 15;
  int m = mt * 64 + wave * 16 + c;
  const bf16* arow = a2 + (size_t)m * EMB + 8 * g;

  __shared__ bf16 wbuf[2][4096];  // 2 x 8KB (two 4KB kc-chunks each)
  const char* wtile = (const char*)wo2f + (size_t)et * 32 * 4096;
  int lofs = lane * 16, wofs = wave * 1024;

#define STAGEW(J, BUF)                                                        \
  {                                                                           \
    const char* src_ = wtile + (size_t)(J) * 8192 + wofs + lofs;              \
    char* dst_ = (char*)&wbuf[BUF][0] + wofs;                                 \
    GL16(src_, dst_);                                                         \
    GL16(src_ + 4096, dst_ + 4096);                                           \
  }

  STAGEW(0, 0);
  bf16x8 bn0 = *(const bf16x8*)(arow);
  bf16x8 bn1 = *(const bf16x8*)(arow + 32);
  __syncthreads();

  f32x4 acc[4];
#pragma unroll
  for (int t = 0; t < 4; ++t) acc[t] = (f32x4){0.f, 0.f, 0.f, 0.f};

  for (int j = 0; j < 16; ++j) {
    int cur = j & 1;
    bf16x8 b0 = bn0, b1 = bn1;
    if (j < 15) {
      STAGEW(j + 1, cur ^ 1);
      bn0 = *(const bf16x8*)(arow + (j + 1) * 64);
      bn1 = *(const bf16x8*)(arow + (j + 1) * 64 + 32);
    }
    const bf16* wb = &wbuf[cur][0];
#pragma unroll
    for (int t = 0; t < 4; ++t)
      acc[t] = mfma16(*(const bf16x8*)(wb + t * 512 + lane * 8), b0, acc[t]);
#pragma unroll
    for (int t = 0; t < 4; ++t)
      acc[t] =
          mfma16(*(const bf16x8*)(wb + 2048 + t * 512 + lane * 8), b1, acc[t]);
    __syncthreads();
  }
#pragma unroll
  for (int t = 0; t < 4; ++t) {
    int e = et * 64 + 16 * t + 4 * g;
    f32x4 b = *(const f32x4*)(bo + e);
    f32x4 w;
#pragma unroll
    for (int r = 0; r < 4; ++r) w[r] = acc[t][r] + b[r];
    *(f32x4*)(out + (size_t)m * EMB + e) = w;
  }
}

extern "C" void kernel_launch(void* const* d_in, const int* in_sizes, int n_in,
                              void* d_out, int out_size, void* d_ws, size_t ws_size,
                              hipStream_t stream) {
  const float* values = (const float*)d_in[0];
  const float* keys   = (const float*)d_in[1];
  const float* query  = (const float*)d_in[2];
  const int*   mask   = (const int*)d_in[3];
  const float* Wv     = (const float*)d_in[4];
  const float* Wk     = (const float*)d_in[5];
  const float* Wq     = (const float*)d_in[6];
  const float* Wo     = (const float*)d_in[7];
  const float* bo     = (const float*)d_in[8];

  char* ws = (char*)d_ws;
  bf16* mqk  = (bf16*)(ws + OFF_MQK);
  bf16* wo2f = (bf16*)(ws + OFF_WO2);
  bf16* k2f  = (bf16*)(ws + OFF_K2);
  bf16* vtf  = (bf16*)(ws + OFF_VT);
  bf16* a2   = (bf16*)(ws + OFF_A2);
  u64*  mbt  = (u64*)(ws + OFF_MB);

  prep0<<<1, 256, 0, stream>>>(Wq, Wk, mqk);
  prep_fused<<<5120, 256, 0, stream>>>(Wo, Wv, keys, mqk, values, mask,
                                       wo2f, k2f, vtf, mbt);
  attn<<<2048, 64, 0, stream>>>(query, k2f, vtf, mbt, a2);
  out_gemm<<<1024, 256, 0, stream>>>(a2, wo2f, bo, (float*)d_out);
}